// Round 1
// baseline (253.967 us; speedup 1.0000x reference)
//
#include <hip/hip_runtime.h>

// ---------------------------------------------------------------------------
// GNN 2-layer via bf16 MFMA + CSR gather (no atomics in hot path).
// This revision: 10 launches -> 6.
//   K1: pack_w  ||  binA            (independent, block-range split)
//   K2: binB    (B1+B2 merged; cursors to matc to avoid RW race)
//   K3: binC    ||  gemm1           (independent, block-range split)
//   K4: binD
//   K5: gemm2_fused                 (gather1 -> LDS (swizzled) -> GEMM2)
//   K6: gather_bf (layer-2 scatter-sum -> out[:, :128] fp32)
// agg1 never touches global memory anymore (25.6 MB HBM saved / iter).
// ws: m1bf | m2bf | W1p | W2p | mat | matc | bb | offs | tmp(int2) | bsrc
// ---------------------------------------------------------------------------

#define D 128
#define CBLK 256         // coarse-binning blocks (phases A and C)
#define DCAP 8192        // max edges per coarse bucket for LDS path

typedef __attribute__((ext_vector_type(8))) short short8;
typedef __attribute__((ext_vector_type(4))) float float4v;
typedef unsigned short ushort_t;
typedef unsigned int uint_t;

static __device__ __forceinline__ ushort_t f2bf(float f) {
    uint_t u = __builtin_bit_cast(uint_t, f);
    u += 0x7FFFu + ((u >> 16) & 1u);           // RNE
    return (ushort_t)(u >> 16);
}
static __device__ __forceinline__ float bfhi(uint_t u) {
    return __builtin_bit_cast(float, u & 0xFFFF0000u);
}
static __device__ __forceinline__ float bflo(uint_t u) {
    return __builtin_bit_cast(float, u << 16);
}

// ---------------- K1: pack both W (B-frag layout)  ||  binA -----------------
// blocks [0,CBLK): coarse histogram (bucket = dst>>8) -> mat[b][c]
// blocks [CBLK, CBLK+24): weight packing
__global__ __launch_bounds__(256) void packw_binA(
    const float* __restrict__ W1, const float* __restrict__ W2,
    ushort_t* __restrict__ W1p, ushort_t* __restrict__ W2p,
    const int* __restrict__ dst, int* __restrict__ mat, int E, int NB)
{
    __shared__ int h[256];
    if (blockIdx.x < CBLK) {
        const int c = blockIdx.x;
        for (int i = threadIdx.x; i < NB; i += 256) h[i] = 0;
        __syncthreads();
        const int chunk = (E + CBLK - 1) / CBLK;
        int e0 = c * chunk, e1 = e0 + chunk; if (e1 > E) e1 = E;
        for (int e = e0 + threadIdx.x; e < e1; e += 256)
            atomicAdd(&h[dst[e] >> 8], 1);
        __syncthreads();
        for (int i = threadIdx.x; i < NB; i += 256)
            mat[i * CBLK + c] = h[i];
        return;
    }
    const int n1 = 4 * 8 * 64;
    const int n2 = 8 * 8 * 64;
    int t = (blockIdx.x - CBLK) * 256 + threadIdx.x;
    if (t >= n1 + n2) return;
    const float* W; ushort_t* Wp; int tt;
    if (t < n1) { W = W1; Wp = W1p; tt = t; }
    else        { W = W2; Wp = W2p; tt = t - n1; }
    int lane = tt & 63, cg = (tt >> 6) & 7, kb = tt >> 9;
    int krow = kb * 32 + (lane >> 4) * 8;
    int col  = cg * 16 + (lane & 15);
    #pragma unroll
    for (int j = 0; j < 8; ++j)
        Wp[(size_t)tt * 8 + j] = f2bf(W[(size_t)(krow + j) * D + col]);
}

// ---------------- K2: binB (merged B1+B2) -----------------------------------
// grid = NB blocks. Each block: bucket totals (thread t sums row t of mat),
// exclusive scan -> bb prefix; then scans its own row -> cursors in matc.
// mat stays read-only here (matc is the write target) so there is no race.
__global__ __launch_bounds__(256) void binB(
    const int* __restrict__ mat, int* __restrict__ matc,
    int* __restrict__ bb, int* __restrict__ offs, int E, int N, int NB)
{
    __shared__ int s[256];
    __shared__ int ex[256];
    const int b = blockIdx.x;
    const int tid = threadIdx.x;

    int v = 0;
    if (tid < NB) {
        const int* row = &mat[tid * CBLK];
        for (int c = 0; c < CBLK; ++c) v += row[c];
    }
    s[tid] = v; __syncthreads();
    for (int o = 1; o < 256; o <<= 1) {
        int t = (tid >= o) ? s[tid - o] : 0;
        __syncthreads();
        s[tid] += t;
        __syncthreads();
    }
    ex[tid] = s[tid] - v;
    __syncthreads();
    if (b == 0) {
        if (tid < NB) bb[tid] = ex[tid];
        if (tid == 0) { bb[NB] = E; offs[N] = E; }
    }
    const int bbb = ex[b];

    int v2 = mat[b * CBLK + tid];
    __syncthreads();
    s[tid] = v2; __syncthreads();
    for (int o = 1; o < 256; o <<= 1) {
        int t = (tid >= o) ? s[tid - o] : 0;
        __syncthreads();
        s[tid] += t;
        __syncthreads();
    }
    matc[b * CBLK + tid] = bbb + s[tid] - v2;
}

// ---------------- K3: binC  ||  gemm1 ---------------------------------------
// blocks [0,CBLK): coarse binning -> tmp at private (block,bucket) cursors
// blocks [CBLK, CBLK+gemmBlocks): m1 = bf16(X @ W1 + b1) via MFMA
__global__ __launch_bounds__(256) void binC_gemm1(
    const int* __restrict__ src, const int* __restrict__ dst,
    const int* __restrict__ matc, int2* __restrict__ tmp, int E, int NB,
    const float* __restrict__ X, const ushort_t* __restrict__ Wp,
    const float* __restrict__ bias, ushort_t* __restrict__ Ybf, int N)
{
    __shared__ int base[256];
    __shared__ int lcnt[256];
    if (blockIdx.x < CBLK) {
        const int c = blockIdx.x;
        for (int i = threadIdx.x; i < NB; i += 256) {
            base[i] = matc[i * CBLK + c];
            lcnt[i] = 0;
        }
        __syncthreads();
        const int chunk = (E + CBLK - 1) / CBLK;
        int e0 = c * chunk, e1 = e0 + chunk; if (e1 > E) e1 = E;
        for (int e = e0 + threadIdx.x; e < e1; e += 256) {
            int d = dst[e];
            int b = d >> 8;
            int p = base[b] + atomicAdd(&lcnt[b], 1);
            int2 pr; pr.x = d; pr.y = src[e];
            tmp[p] = pr;
        }
        return;
    }

    // ---- gemm1 ----
    const int wave = threadIdx.x >> 6;
    const int lane = threadIdx.x & 63;
    const int quad = lane >> 4;
    const int l16  = lane & 15;
    const int r0   = (blockIdx.x - CBLK) * 128 + wave * 32;

    float4v acc[2][8];
    #pragma unroll
    for (int cg = 0; cg < 8; ++cg) {
        float bv = bias[cg * 16 + l16];
        float4v b4 = {bv, bv, bv, bv};
        acc[0][cg] = b4; acc[1][cg] = b4;
    }

    const short8* wp8 = (const short8*)Wp;

    #pragma unroll
    for (int kb = 0; kb < 4; ++kb) {
        const int k0 = kb * 32 + quad * 8;
        short8 a[2];
        #pragma unroll
        for (int rb = 0; rb < 2; ++rb) {
            int row = r0 + rb * 16 + l16;
            if (row >= N) row = N - 1;
            const float* p = &X[(size_t)row * D + k0];
            float4 x0 = *(const float4*)p;
            float4 x1 = *(const float4*)(p + 4);
            short8 s;
            s[0] = (short)f2bf(x0.x); s[1] = (short)f2bf(x0.y);
            s[2] = (short)f2bf(x0.z); s[3] = (short)f2bf(x0.w);
            s[4] = (short)f2bf(x1.x); s[5] = (short)f2bf(x1.y);
            s[6] = (short)f2bf(x1.z); s[7] = (short)f2bf(x1.w);
            a[rb] = s;
        }
        #pragma unroll
        for (int cg = 0; cg < 8; ++cg) {
            short8 b = wp8[(kb * 8 + cg) * 64 + lane];
            acc[0][cg] = __builtin_amdgcn_mfma_f32_16x16x32_bf16(a[0], b, acc[0][cg], 0, 0, 0);
            acc[1][cg] = __builtin_amdgcn_mfma_f32_16x16x32_bf16(a[1], b, acc[1][cg], 0, 0, 0);
        }
    }

    #pragma unroll
    for (int rb = 0; rb < 2; ++rb) {
        int rowb = r0 + rb * 16 + quad * 4;
        #pragma unroll
        for (int cg = 0; cg < 8; ++cg) {
            int col = cg * 16 + l16;
            #pragma unroll
            for (int i = 0; i < 4; ++i) {
                int row = rowb + i;
                if (row < N) Ybf[(size_t)row * D + col] = f2bf(acc[rb][cg][i]);
            }
        }
    }
}

// ---------------- K4: binD — per-bucket fine sort ---------------------------
__global__ __launch_bounds__(256) void binD(const int2* __restrict__ tmp,
                                            const int* __restrict__ bb,
                                            int* __restrict__ offs,
                                            int* __restrict__ bsrc, int N, int NB) {
    __shared__ int hist[256];
    __shared__ int foff[256];
    __shared__ int cntf[256];
    __shared__ int outS[DCAP];
    const int b = blockIdx.x;
    const int tid = threadIdx.x;
    const int beg = bb[b], end = bb[b + 1];
    const int cnt = end - beg;
    const int n0 = b << 8;

    hist[tid] = 0;
    __syncthreads();
    for (int i = tid; i < cnt; i += 256)
        atomicAdd(&hist[tmp[beg + i].x & 255], 1);
    __syncthreads();
    int v = hist[tid];
    __syncthreads();
    hist[tid] = v; __syncthreads();
    for (int o = 1; o < 256; o <<= 1) {
        int t = (tid >= o) ? hist[tid - o] : 0;
        __syncthreads();
        hist[tid] += t;
        __syncthreads();
    }
    foff[tid] = hist[tid] - v;
    cntf[tid] = 0;
    __syncthreads();

    int node = n0 + tid;
    if (node < N) offs[node] = beg + foff[tid];

    if (cnt <= DCAP) {
        for (int i = tid; i < cnt; i += 256) {
            int2 p = tmp[beg + i];
            int f = p.x & 255;
            int pos = foff[f] + atomicAdd(&cntf[f], 1);
            outS[pos] = p.y;
        }
        __syncthreads();
        for (int i = tid; i < cnt; i += 256)
            bsrc[beg + i] = outS[i];
    } else {
        for (int i = tid; i < cnt; i += 256) {
            int2 p = tmp[beg + i];
            int f = p.x & 255;
            int pos = foff[f] + atomicAdd(&cntf[f], 1);
            bsrc[beg + pos] = p.y;
        }
    }
}

// ---------------- K5: fused gather1 + GEMM2 ---------------------------------
// Phase 1: block gathers agg1 rows for its 128 output rows into LDS
//          (16B-granule XOR swizzle: granule g of row r stored at g^(r&15)).
// Phase 2: m2 = [agg1(LDS), m1(global)] @ W2 + b2 -> out[:,128:] fp32 + m2bf.
__global__ __launch_bounds__(256) void gemm2_fused(
    const ushort_t* __restrict__ m1bf,     // gather source AND A1 operand
    const int* __restrict__ offs, const int* __restrict__ bsrc,
    const ushort_t* __restrict__ Wp, const float* __restrict__ bias,
    float* __restrict__ Yf, ushort_t* __restrict__ Ybf, int N)
{
    __shared__ uint4 aggS4[128 * 16];      // 128 rows x 16 granules = 32 KiB
    __shared__ int offsS[129];

    const int tid  = threadIdx.x;
    const int wave = tid >> 6;
    const int lane = tid & 63;
    const int quad = lane >> 4;
    const int l16  = lane & 15;
    const int c16  = l16;
    const int n0   = blockIdx.x * 128;
    int nv = N - n0; if (nv > 128) nv = 128;

    for (int t = tid; t <= nv; t += 256) offsS[t] = offs[n0 + t];
    // zero rows >= nv so MFMA A-reads of invalid rows are defined
    {
        uint4 z; z.x = z.y = z.z = z.w = 0u;
        for (int r = nv + (tid >> 4); r < 128; r += 16)
            aggS4[r * 16 + (tid & 15)] = z;
    }
    __syncthreads();

    // ---- phase 1: gather agg1 for local rows [0, nv) ----
    const uint4* mp = (const uint4*)m1bf;  // 16 uint4 per msg row
    for (int i = wave; i < nv; i += 4) {
        int beg = offsS[i], end = offsS[i + 1];
        float ax[4] = {0.f, 0.f, 0.f, 0.f};
        float ay[4] = {0.f, 0.f, 0.f, 0.f};
        for (int base = beg; base < end; base += 64) {
            int cnt = end - base; if (cnt > 64) cnt = 64;
            int sidx = bsrc[base + (lane < cnt ? lane : cnt - 1)];
            for (int j0 = 0; j0 < cnt; j0 += 16) {
                #pragma unroll
                for (int t = 0; t < 4; ++t) {
                    int e  = j0 + t * 4 + quad;
                    int ec = (e < cnt) ? e : cnt - 1;
                    int s  = __shfl(sidx, ec, 64);
                    uint4 u = mp[(size_t)s * 16 + c16];
                    if (e < cnt) {
                        ax[0] += bflo(u.x); ay[0] += bfhi(u.x);
                        ax[1] += bflo(u.y); ay[1] += bfhi(u.y);
                        ax[2] += bflo(u.z); ay[2] += bfhi(u.z);
                        ax[3] += bflo(u.w); ay[3] += bfhi(u.w);
                    }
                }
            }
        }
        #pragma unroll
        for (int k = 0; k < 4; ++k) {
            ax[k] += __shfl_xor(ax[k], 16, 64);
            ax[k] += __shfl_xor(ax[k], 32, 64);
            ay[k] += __shfl_xor(ay[k], 16, 64);
            ay[k] += __shfl_xor(ay[k], 32, 64);
        }
        if (quad == 0) {
            uint4 o;
            o.x = (uint_t)f2bf(ax[0]) | ((uint_t)f2bf(ay[0]) << 16);
            o.y = (uint_t)f2bf(ax[1]) | ((uint_t)f2bf(ay[1]) << 16);
            o.z = (uint_t)f2bf(ax[2]) | ((uint_t)f2bf(ay[2]) << 16);
            o.w = (uint_t)f2bf(ax[3]) | ((uint_t)f2bf(ay[3]) << 16);
            aggS4[i * 16 + (c16 ^ (i & 15))] = o;   // swizzled store
        }
    }
    __syncthreads();

    // ---- phase 2: GEMM2 ----
    const int r0 = n0 + wave * 32;

    float4v acc[2][8];
    #pragma unroll
    for (int cg = 0; cg < 8; ++cg) {
        float bv = bias[cg * 16 + l16];
        float4v b4 = {bv, bv, bv, bv};
        acc[0][cg] = b4; acc[1][cg] = b4;
    }

    const short8* wp8 = (const short8*)Wp;
    const short8* aggS8 = (const short8*)aggS4;

    #pragma unroll
    for (int kb = 0; kb < 8; ++kb) {
        const int k0 = (kb & 3) * 32 + quad * 8;
        short8 a[2];
        if (kb < 4) {
            const int g = (kb & 3) * 4 + quad;      // 16B granule index
            #pragma unroll
            for (int rb = 0; rb < 2; ++rb) {
                int li = wave * 32 + rb * 16 + l16; // local row
                a[rb] = aggS8[li * 16 + (g ^ (li & 15))];   // swizzled read
            }
        } else {
            #pragma unroll
            for (int rb = 0; rb < 2; ++rb) {
                int row = r0 + rb * 16 + l16;
                if (row >= N) row = N - 1;
                a[rb] = *(const short8*)&m1bf[(size_t)row * D + k0];
            }
        }
        #pragma unroll
        for (int cg = 0; cg < 8; ++cg) {
            short8 b = wp8[(kb * 8 + cg) * 64 + lane];
            acc[0][cg] = __builtin_amdgcn_mfma_f32_16x16x32_bf16(a[0], b, acc[0][cg], 0, 0, 0);
            acc[1][cg] = __builtin_amdgcn_mfma_f32_16x16x32_bf16(a[1], b, acc[1][cg], 0, 0, 0);
        }
    }

    #pragma unroll
    for (int rb = 0; rb < 2; ++rb) {
        int rowb = r0 + rb * 16 + quad * 4;
        #pragma unroll
        for (int cg = 0; cg < 8; ++cg) {
            int col = cg * 16 + l16;
            #pragma unroll
            for (int i = 0; i < 4; ++i) {
                int row = rowb + i;
                if (row < N) {
                    float v = acc[rb][cg][i];
                    Yf[(size_t)row * 256 + col] = v;
                    Ybf[(size_t)row * D + col] = f2bf(v);
                }
            }
        }
    }
}

// ---------------- K6: gather-sum (layer 2) -> fp32 out[:, :128] -------------
__global__ __launch_bounds__(256) void gather_bf(
    const ushort_t* __restrict__ msg,            // [N][128] bf16
    const int* __restrict__ offs, const int* __restrict__ bsrc,
    float* __restrict__ aggF,                    // fp32 out (stride 256)
    int N)
{
    int node = (blockIdx.x * 256 + threadIdx.x) >> 6;
    int lane = threadIdx.x & 63;
    if (node >= N) return;
    const int quad = lane >> 4;
    const int c16  = lane & 15;
    int beg = offs[node], end = offs[node + 1];

    float ax[4] = {0.f, 0.f, 0.f, 0.f};
    float ay[4] = {0.f, 0.f, 0.f, 0.f};
    const uint4* mp = (const uint4*)msg;

    for (int base = beg; base < end; base += 64) {
        int cnt = end - base; if (cnt > 64) cnt = 64;
        int sidx = bsrc[base + (lane < cnt ? lane : cnt - 1)];
        for (int j0 = 0; j0 < cnt; j0 += 16) {
            #pragma unroll
            for (int t = 0; t < 4; ++t) {
                int e  = j0 + t * 4 + quad;
                int ec = (e < cnt) ? e : cnt - 1;
                int s  = __shfl(sidx, ec, 64);
                uint4 u = mp[(size_t)s * 16 + c16];
                if (e < cnt) {
                    ax[0] += bflo(u.x); ay[0] += bfhi(u.x);
                    ax[1] += bflo(u.y); ay[1] += bfhi(u.y);
                    ax[2] += bflo(u.z); ay[2] += bfhi(u.z);
                    ax[3] += bflo(u.w); ay[3] += bfhi(u.w);
                }
            }
        }
    }

    #pragma unroll
    for (int k = 0; k < 4; ++k) {
        ax[k] += __shfl_xor(ax[k], 16, 64);
        ax[k] += __shfl_xor(ax[k], 32, 64);
        ay[k] += __shfl_xor(ay[k], 16, 64);
        ay[k] += __shfl_xor(ay[k], 32, 64);
    }

    if (quad == 0) {
        float4 w0 = {ax[0], ay[0], ax[1], ay[1]};
        float4 w1 = {ax[2], ay[2], ax[3], ay[3]};
        float* p = &aggF[(size_t)node * 256 + c16 * 8];
        *(float4*)p = w0;
        *(float4*)(p + 4) = w1;
    }
}

// ---------------------------------------------------------------------------
extern "C" void kernel_launch(void* const* d_in, const int* in_sizes, int n_in,
                              void* d_out, int out_size, void* d_ws, size_t ws_size,
                              hipStream_t stream) {
    const float* features = (const float*)d_in[0];
    const int*   src      = (const int*)d_in[1];
    const int*   dst      = (const int*)d_in[2];
    const float* W1       = (const float*)d_in[3];
    const float* b1       = (const float*)d_in[4];
    const float* W2       = (const float*)d_in[5];
    const float* b2       = (const float*)d_in[6];
    float* out = (float*)d_out;

    const int N = in_sizes[0] / D;   // 50000
    const int E = in_sizes[1];       // 800000
    const int NB = (N + 255) >> 8;   // 196 coarse buckets (<=256 required)

    // ws carve-up
    ushort_t* m1bf = (ushort_t*)d_ws;                   // N*D
    ushort_t* m2bf = m1bf + (size_t)N * D;              // N*D
    ushort_t* W1p  = m2bf + (size_t)N * D;              // 16384
    ushort_t* W2p  = W1p + 16384;                       // 32768
    int*  mat  = (int*)(W2p + 32768);                   // NB*CBLK (histograms)
    int*  matc = mat + (size_t)NB * CBLK;               // NB*CBLK (cursors)
    int*  bb   = matc + (size_t)NB * CBLK;              // NB+1
    int*  offs = bb + NB + 1;                           // N+1
    int2* tmp  = (int2*)(offs + N + 1);                 // E pairs
    int*  bsrc = (int*)(tmp + (size_t)E);               // E

    const int gemmBlocks = (N + 127) / 128;

    // K1: weight pack || coarse histogram
    packw_binA<<<CBLK + 24, 256, 0, stream>>>(W1, W2, W1p, W2p, dst, mat, E, NB);
    // K2: merged scans -> bucket bases (bb) + per-block cursors (matc)
    binB<<<NB, 256, 0, stream>>>(mat, matc, bb, offs, E, N, NB);
    // K3: coarse binning || layer-1 GEMM
    binC_gemm1<<<CBLK + gemmBlocks, 256, 0, stream>>>(src, dst, matc, tmp, E, NB,
                                                      features, W1p, b1, m1bf, N);
    // K4: fine sort -> offs + bsrc
    binD<<<NB, 256, 0, stream>>>(tmp, bb, offs, bsrc, N, NB);
    // K5: gather1 (LDS) + GEMM2 -> out[:,128:] fp32 + m2bf
    gemm2_fused<<<gemmBlocks, 256, 0, stream>>>(m1bf, offs, bsrc, W2p, b2,
                                                out + D, m2bf, N);
    // K6: layer-2 gather -> out[:, :128]
    gather_bf<<<(N * 64 + 255) / 256, 256, 0, stream>>>(m2bf, offs, bsrc, out, N);
}

// Round 2
// 208.533 us; speedup vs baseline: 1.2179x; 1.2179x over previous
//
#include <hip/hip_runtime.h>

// ---------------------------------------------------------------------------
// GNN 2-layer via bf16 MFMA + CSR gather (no atomics in hot path).
// 7 launches (Round-1 fusion of gather1 into gemm2 reverted: the gather is
// latency-bound and needs one wave per node = 50000 waves; fusing it into
// 391 GEMM blocks collapsed parallelism and cost +55us).
//   K1: pack_w  ||  binA            (independent, block-range split)
//   K2: binB    (B1+B2 merged; cursors to matc to avoid RW race)
//   K3: binC    ||  gemm1           (independent, block-range split)
//   K4: binD
//   K5: gather_bf (layer 1) -> agg1bf (bf16)
//   K6: gemm2_mfma                  -> out[:,128:] fp32 + m2bf
//   K7: gather_bf (layer 2) -> out[:, :128] fp32
// ws: m1bf | agg1bf | m2bf | W1p | W2p | mat | matc | bb | offs | tmp | bsrc
// ---------------------------------------------------------------------------

#define D 128
#define CBLK 256         // coarse-binning blocks (phases A and C)
#define DCAP 8192        // max edges per coarse bucket for LDS path

typedef __attribute__((ext_vector_type(8))) short short8;
typedef __attribute__((ext_vector_type(4))) float float4v;
typedef unsigned short ushort_t;
typedef unsigned int uint_t;

static __device__ __forceinline__ ushort_t f2bf(float f) {
    uint_t u = __builtin_bit_cast(uint_t, f);
    u += 0x7FFFu + ((u >> 16) & 1u);           // RNE
    return (ushort_t)(u >> 16);
}
static __device__ __forceinline__ float bfhi(uint_t u) {
    return __builtin_bit_cast(float, u & 0xFFFF0000u);
}
static __device__ __forceinline__ float bflo(uint_t u) {
    return __builtin_bit_cast(float, u << 16);
}

// ---------------- K1: pack both W (B-frag layout)  ||  binA -----------------
__global__ __launch_bounds__(256) void packw_binA(
    const float* __restrict__ W1, const float* __restrict__ W2,
    ushort_t* __restrict__ W1p, ushort_t* __restrict__ W2p,
    const int* __restrict__ dst, int* __restrict__ mat, int E, int NB)
{
    __shared__ int h[256];
    if (blockIdx.x < CBLK) {
        const int c = blockIdx.x;
        for (int i = threadIdx.x; i < NB; i += 256) h[i] = 0;
        __syncthreads();
        const int chunk = (E + CBLK - 1) / CBLK;
        int e0 = c * chunk, e1 = e0 + chunk; if (e1 > E) e1 = E;
        for (int e = e0 + threadIdx.x; e < e1; e += 256)
            atomicAdd(&h[dst[e] >> 8], 1);
        __syncthreads();
        for (int i = threadIdx.x; i < NB; i += 256)
            mat[i * CBLK + c] = h[i];
        return;
    }
    const int n1 = 4 * 8 * 64;
    const int n2 = 8 * 8 * 64;
    int t = (blockIdx.x - CBLK) * 256 + threadIdx.x;
    if (t >= n1 + n2) return;
    const float* W; ushort_t* Wp; int tt;
    if (t < n1) { W = W1; Wp = W1p; tt = t; }
    else        { W = W2; Wp = W2p; tt = t - n1; }
    int lane = tt & 63, cg = (tt >> 6) & 7, kb = tt >> 9;
    int krow = kb * 32 + (lane >> 4) * 8;
    int col  = cg * 16 + (lane & 15);
    #pragma unroll
    for (int j = 0; j < 8; ++j)
        Wp[(size_t)tt * 8 + j] = f2bf(W[(size_t)(krow + j) * D + col]);
}

// ---------------- K2: binB (merged B1+B2) -----------------------------------
__global__ __launch_bounds__(256) void binB(
    const int* __restrict__ mat, int* __restrict__ matc,
    int* __restrict__ bb, int* __restrict__ offs, int E, int N, int NB)
{
    __shared__ int s[256];
    __shared__ int ex[256];
    const int b = blockIdx.x;
    const int tid = threadIdx.x;

    int v = 0;
    if (tid < NB) {
        const int* row = &mat[tid * CBLK];
        for (int c = 0; c < CBLK; ++c) v += row[c];
    }
    s[tid] = v; __syncthreads();
    for (int o = 1; o < 256; o <<= 1) {
        int t = (tid >= o) ? s[tid - o] : 0;
        __syncthreads();
        s[tid] += t;
        __syncthreads();
    }
    ex[tid] = s[tid] - v;
    __syncthreads();
    if (b == 0) {
        if (tid < NB) bb[tid] = ex[tid];
        if (tid == 0) { bb[NB] = E; offs[N] = E; }
    }
    const int bbb = ex[b];

    int v2 = mat[b * CBLK + tid];
    __syncthreads();
    s[tid] = v2; __syncthreads();
    for (int o = 1; o < 256; o <<= 1) {
        int t = (tid >= o) ? s[tid - o] : 0;
        __syncthreads();
        s[tid] += t;
        __syncthreads();
    }
    matc[b * CBLK + tid] = bbb + s[tid] - v2;
}

// ---------------- K3: binC  ||  gemm1 ---------------------------------------
__global__ __launch_bounds__(256) void binC_gemm1(
    const int* __restrict__ src, const int* __restrict__ dst,
    const int* __restrict__ matc, int2* __restrict__ tmp, int E, int NB,
    const float* __restrict__ X, const ushort_t* __restrict__ Wp,
    const float* __restrict__ bias, ushort_t* __restrict__ Ybf, int N)
{
    __shared__ int base[256];
    __shared__ int lcnt[256];
    if (blockIdx.x < CBLK) {
        const int c = blockIdx.x;
        for (int i = threadIdx.x; i < NB; i += 256) {
            base[i] = matc[i * CBLK + c];
            lcnt[i] = 0;
        }
        __syncthreads();
        const int chunk = (E + CBLK - 1) / CBLK;
        int e0 = c * chunk, e1 = e0 + chunk; if (e1 > E) e1 = E;
        for (int e = e0 + threadIdx.x; e < e1; e += 256) {
            int d = dst[e];
            int b = d >> 8;
            int p = base[b] + atomicAdd(&lcnt[b], 1);
            int2 pr; pr.x = d; pr.y = src[e];
            tmp[p] = pr;
        }
        return;
    }

    // ---- gemm1: m1 = bf16(X @ W1 + b1) ----
    const int wave = threadIdx.x >> 6;
    const int lane = threadIdx.x & 63;
    const int quad = lane >> 4;
    const int l16  = lane & 15;
    const int r0   = (blockIdx.x - CBLK) * 128 + wave * 32;

    float4v acc[2][8];
    #pragma unroll
    for (int cg = 0; cg < 8; ++cg) {
        float bv = bias[cg * 16 + l16];
        float4v b4 = {bv, bv, bv, bv};
        acc[0][cg] = b4; acc[1][cg] = b4;
    }

    const short8* wp8 = (const short8*)Wp;

    #pragma unroll
    for (int kb = 0; kb < 4; ++kb) {
        const int k0 = kb * 32 + quad * 8;
        short8 a[2];
        #pragma unroll
        for (int rb = 0; rb < 2; ++rb) {
            int row = r0 + rb * 16 + l16;
            if (row >= N) row = N - 1;
            const float* p = &X[(size_t)row * D + k0];
            float4 x0 = *(const float4*)p;
            float4 x1 = *(const float4*)(p + 4);
            short8 s;
            s[0] = (short)f2bf(x0.x); s[1] = (short)f2bf(x0.y);
            s[2] = (short)f2bf(x0.z); s[3] = (short)f2bf(x0.w);
            s[4] = (short)f2bf(x1.x); s[5] = (short)f2bf(x1.y);
            s[6] = (short)f2bf(x1.z); s[7] = (short)f2bf(x1.w);
            a[rb] = s;
        }
        #pragma unroll
        for (int cg = 0; cg < 8; ++cg) {
            short8 b = wp8[(kb * 8 + cg) * 64 + lane];
            acc[0][cg] = __builtin_amdgcn_mfma_f32_16x16x32_bf16(a[0], b, acc[0][cg], 0, 0, 0);
            acc[1][cg] = __builtin_amdgcn_mfma_f32_16x16x32_bf16(a[1], b, acc[1][cg], 0, 0, 0);
        }
    }

    #pragma unroll
    for (int rb = 0; rb < 2; ++rb) {
        int rowb = r0 + rb * 16 + quad * 4;
        #pragma unroll
        for (int cg = 0; cg < 8; ++cg) {
            int col = cg * 16 + l16;
            #pragma unroll
            for (int i = 0; i < 4; ++i) {
                int row = rowb + i;
                if (row < N) Ybf[(size_t)row * D + col] = f2bf(acc[rb][cg][i]);
            }
        }
    }
}

// ---------------- K4: binD — per-bucket fine sort ---------------------------
__global__ __launch_bounds__(256) void binD(const int2* __restrict__ tmp,
                                            const int* __restrict__ bb,
                                            int* __restrict__ offs,
                                            int* __restrict__ bsrc, int N, int NB) {
    __shared__ int hist[256];
    __shared__ int foff[256];
    __shared__ int cntf[256];
    __shared__ int outS[DCAP];
    const int b = blockIdx.x;
    const int tid = threadIdx.x;
    const int beg = bb[b], end = bb[b + 1];
    const int cnt = end - beg;
    const int n0 = b << 8;

    hist[tid] = 0;
    __syncthreads();
    for (int i = tid; i < cnt; i += 256)
        atomicAdd(&hist[tmp[beg + i].x & 255], 1);
    __syncthreads();
    int v = hist[tid];
    __syncthreads();
    hist[tid] = v; __syncthreads();
    for (int o = 1; o < 256; o <<= 1) {
        int t = (tid >= o) ? hist[tid - o] : 0;
        __syncthreads();
        hist[tid] += t;
        __syncthreads();
    }
    foff[tid] = hist[tid] - v;
    cntf[tid] = 0;
    __syncthreads();

    int node = n0 + tid;
    if (node < N) offs[node] = beg + foff[tid];

    if (cnt <= DCAP) {
        for (int i = tid; i < cnt; i += 256) {
            int2 p = tmp[beg + i];
            int f = p.x & 255;
            int pos = foff[f] + atomicAdd(&cntf[f], 1);
            outS[pos] = p.y;
        }
        __syncthreads();
        for (int i = tid; i < cnt; i += 256)
            bsrc[beg + i] = outS[i];
    } else {
        for (int i = tid; i < cnt; i += 256) {
            int2 p = tmp[beg + i];
            int f = p.x & 255;
            int pos = foff[f] + atomicAdd(&cntf[f], 1);
            bsrc[beg + pos] = p.y;
        }
    }
}

// ---------------- K6: MFMA GEMM 2: bf16 A0/A1 -> fp32 Y + bf16 copy ---------
__global__ __launch_bounds__(256) void gemm2_mfma(
    const ushort_t* __restrict__ A0, const ushort_t* __restrict__ A1,
    const ushort_t* __restrict__ Wp, const float* __restrict__ bias,
    float* __restrict__ Yf, ushort_t* __restrict__ Ybf, int N)
{
    const int wave = threadIdx.x >> 6;
    const int lane = threadIdx.x & 63;
    const int quad = lane >> 4;
    const int l16  = lane & 15;
    const int r0   = blockIdx.x * 128 + wave * 32;

    float4v acc[2][8];
    #pragma unroll
    for (int cg = 0; cg < 8; ++cg) {
        float bv = bias[cg * 16 + l16];
        float4v b4 = {bv, bv, bv, bv};
        acc[0][cg] = b4; acc[1][cg] = b4;
    }

    const short8* wp8 = (const short8*)Wp;

    #pragma unroll
    for (int kb = 0; kb < 8; ++kb) {
        const ushort_t* __restrict__ A = (kb < 4) ? A0 : A1;
        const int k0 = (kb & 3) * 32 + quad * 8;
        short8 a[2];
        #pragma unroll
        for (int rb = 0; rb < 2; ++rb) {
            int row = r0 + rb * 16 + l16;
            if (row >= N) row = N - 1;
            a[rb] = *(const short8*)&A[(size_t)row * D + k0];
        }
        #pragma unroll
        for (int cg = 0; cg < 8; ++cg) {
            short8 b = wp8[(kb * 8 + cg) * 64 + lane];
            acc[0][cg] = __builtin_amdgcn_mfma_f32_16x16x32_bf16(a[0], b, acc[0][cg], 0, 0, 0);
            acc[1][cg] = __builtin_amdgcn_mfma_f32_16x16x32_bf16(a[1], b, acc[1][cg], 0, 0, 0);
        }
    }

    #pragma unroll
    for (int rb = 0; rb < 2; ++rb) {
        int rowb = r0 + rb * 16 + quad * 4;
        #pragma unroll
        for (int cg = 0; cg < 8; ++cg) {
            int col = cg * 16 + l16;
            #pragma unroll
            for (int i = 0; i < 4; ++i) {
                int row = rowb + i;
                if (row < N) {
                    float v = acc[rb][cg][i];
                    Yf[(size_t)row * 256 + col] = v;
                    Ybf[(size_t)row * D + col] = f2bf(v);
                }
            }
        }
    }
}

// ---------------- K5/K7: gather-sum over CSR (bf16 msg), quad-split ---------
__global__ __launch_bounds__(256) void gather_bf(
    const ushort_t* __restrict__ msg,            // [N][128] bf16
    const int* __restrict__ offs, const int* __restrict__ bsrc,
    ushort_t* __restrict__ aggB,                 // bf16 out [N][128], or null
    float* __restrict__ aggF,                    // fp32 out (stride 256), or null
    int N)
{
    int node = (blockIdx.x * 256 + threadIdx.x) >> 6;
    int lane = threadIdx.x & 63;
    if (node >= N) return;
    const int quad = lane >> 4;
    const int c16  = lane & 15;
    int beg = offs[node], end = offs[node + 1];

    float ax[4] = {0.f, 0.f, 0.f, 0.f};
    float ay[4] = {0.f, 0.f, 0.f, 0.f};
    const uint4* mp = (const uint4*)msg;         // 16 uint4 per row

    for (int base = beg; base < end; base += 64) {
        int cnt = end - base; if (cnt > 64) cnt = 64;
        int sidx = bsrc[base + (lane < cnt ? lane : cnt - 1)];
        for (int j0 = 0; j0 < cnt; j0 += 16) {
            #pragma unroll
            for (int t = 0; t < 4; ++t) {
                int e  = j0 + t * 4 + quad;
                int ec = (e < cnt) ? e : cnt - 1;
                int s  = __shfl(sidx, ec, 64);
                uint4 u = mp[(size_t)s * 16 + c16];
                if (e < cnt) {
                    ax[0] += bflo(u.x); ay[0] += bfhi(u.x);
                    ax[1] += bflo(u.y); ay[1] += bfhi(u.y);
                    ax[2] += bflo(u.z); ay[2] += bfhi(u.z);
                    ax[3] += bflo(u.w); ay[3] += bfhi(u.w);
                }
            }
        }
    }

    #pragma unroll
    for (int k = 0; k < 4; ++k) {
        ax[k] += __shfl_xor(ax[k], 16, 64);
        ax[k] += __shfl_xor(ax[k], 32, 64);
        ay[k] += __shfl_xor(ay[k], 16, 64);
        ay[k] += __shfl_xor(ay[k], 32, 64);
    }

    if (quad == 0) {
        if (aggB) {
            uint4 o;
            o.x = (uint_t)f2bf(ax[0]) | ((uint_t)f2bf(ay[0]) << 16);
            o.y = (uint_t)f2bf(ax[1]) | ((uint_t)f2bf(ay[1]) << 16);
            o.z = (uint_t)f2bf(ax[2]) | ((uint_t)f2bf(ay[2]) << 16);
            o.w = (uint_t)f2bf(ax[3]) | ((uint_t)f2bf(ay[3]) << 16);
            ((uint4*)aggB)[(size_t)node * 16 + c16] = o;
        } else {
            float4 w0 = {ax[0], ay[0], ax[1], ay[1]};
            float4 w1 = {ax[2], ay[2], ax[3], ay[3]};
            float* p = &aggF[(size_t)node * 256 + c16 * 8];
            *(float4*)p = w0;
            *(float4*)(p + 4) = w1;
        }
    }
}

// ---------------------------------------------------------------------------
extern "C" void kernel_launch(void* const* d_in, const int* in_sizes, int n_in,
                              void* d_out, int out_size, void* d_ws, size_t ws_size,
                              hipStream_t stream) {
    const float* features = (const float*)d_in[0];
    const int*   src      = (const int*)d_in[1];
    const int*   dst      = (const int*)d_in[2];
    const float* W1       = (const float*)d_in[3];
    const float* b1       = (const float*)d_in[4];
    const float* W2       = (const float*)d_in[5];
    const float* b2       = (const float*)d_in[6];
    float* out = (float*)d_out;

    const int N = in_sizes[0] / D;   // 50000
    const int E = in_sizes[1];       // 800000
    const int NB = (N + 255) >> 8;   // 196 coarse buckets (<=256 required)

    // ws carve-up
    ushort_t* m1bf   = (ushort_t*)d_ws;                 // N*D
    ushort_t* agg1bf = m1bf + (size_t)N * D;            // N*D
    ushort_t* m2bf   = agg1bf + (size_t)N * D;          // N*D
    ushort_t* W1p    = m2bf + (size_t)N * D;            // 16384
    ushort_t* W2p    = W1p + 16384;                     // 32768
    int*  mat  = (int*)(W2p + 32768);                   // NB*CBLK (histograms)
    int*  matc = mat + (size_t)NB * CBLK;               // NB*CBLK (cursors)
    int*  bb   = matc + (size_t)NB * CBLK;              // NB+1
    int*  offs = bb + NB + 1;                           // N+1
    int2* tmp  = (int2*)(offs + N + 1);                 // E pairs
    int*  bsrc = (int*)(tmp + (size_t)E);               // E

    const int gemmBlocks = (N + 127) / 128;

    // K1: weight pack || coarse histogram
    packw_binA<<<CBLK + 24, 256, 0, stream>>>(W1, W2, W1p, W2p, dst, mat, E, NB);
    // K2: merged scans -> bucket bases (bb) + per-block cursors (matc)
    binB<<<NB, 256, 0, stream>>>(mat, matc, bb, offs, E, N, NB);
    // K3: coarse binning || layer-1 GEMM
    binC_gemm1<<<CBLK + gemmBlocks, 256, 0, stream>>>(src, dst, matc, tmp, E, NB,
                                                      features, W1p, b1, m1bf, N);
    // K4: fine sort -> offs + bsrc
    binD<<<NB, 256, 0, stream>>>(tmp, bb, offs, bsrc, N, NB);
    // K5: layer-1 gather -> agg1bf (bf16)
    gather_bf<<<(N * 64 + 255) / 256, 256, 0, stream>>>(m1bf, offs, bsrc,
                                                        agg1bf, nullptr, N);
    // K6: layer-2 GEMM -> out[:,128:] fp32 + m2bf
    gemm2_mfma<<<gemmBlocks, 256, 0, stream>>>(agg1bf, m1bf, W2p, b2,
                                               out + D, m2bf, N);
    // K7: layer-2 gather -> out[:, :128]
    gather_bf<<<(N * 64 + 255) / 256, 256, 0, stream>>>(m2bf, offs, bsrc,
                                                        nullptr, out, N);
}